// Round 6
// baseline (220.223 us; speedup 1.0000x reference)
//
#include <hip/hip_runtime.h>
#include <hip/hip_bf16.h>
#include <math.h>

typedef unsigned short u16;
typedef __bf16 bf16x8 __attribute__((ext_vector_type(8)));
typedef float  f32x16 __attribute__((ext_vector_type(16)));
typedef u16    u16x8  __attribute__((ext_vector_type(8)));
typedef u16    u16x4  __attribute__((ext_vector_type(4)));

#define BATCH 16
#define T0 64000
#define T1 32000
#define T2 16000
#define T3 8000
#define NT3 124          // t3 outputs per mega block; 65 blocks x 124 >= 8000
#define NBLK 65
#define NROWS1 528       // local y1 rows staged (incl. 8 guard rows; 264 lines)
#define NL2 256          // y2 rows per block (2*124+8)

static __device__ __forceinline__ u16 f2bf(float f) {
    __hip_bfloat16 h = __float2bfloat16(f);
    return *reinterpret_cast<u16*>(&h);
}
static __device__ __forceinline__ float bf2f(u16 u) {
    __hip_bfloat16 h;
    *reinterpret_cast<u16*>(&h) = u;
    return __bfloat162float(h);
}

// ---------------- weight prep + pooled zero-init
// a2t[c][g][o][j]: c=kk*2+part (18), g=0..3 (i-granule), o=0..63, j=0..7 (i=8g+j)
// a3t[c][g][o][j]: c (18), g=0..7, o=0..127, j=0..7
__global__ __launch_bounds__(256) void prep_w_k(const float* __restrict__ w2,
                                                const float* __restrict__ w3,
                                                u16* __restrict__ a2t,
                                                u16* __restrict__ a3t,
                                                float* __restrict__ pooled) {
    int idx = blockIdx.x * 256 + threadIdx.x;
    if (idx < 36864) {
        int j = idx & 7, o = (idx >> 3) & 63, g = (idx >> 9) & 3, c = idx >> 11;
        int kk = c >> 1, part = c & 1, i = g * 8 + j;
        float v = w2[(o * 32 + i) * 9 + kk];
        u16 hv = f2bf(v);
        if (part) hv = f2bf(v - bf2f(hv));
        a2t[idx] = hv;
    } else if (idx < 36864 + 147456) {
        int jdx = idx - 36864;
        int j = jdx & 7, o = (jdx >> 3) & 127, g = (jdx >> 10) & 7, c = jdx >> 13;
        int kk = c >> 1, part = c & 1, i = g * 8 + j;
        float v = w3[(o * 64 + i) * 9 + kk];
        u16 hv = f2bf(v);
        if (part) hv = f2bf(v - bf2f(hv));
        a3t[jdx] = hv;
    } else if (idx < 36864 + 147456 + 2048) {
        pooled[idx - 36864 - 147456] = 0.f;
    }
}

// ---------------- mega: conv1(VALU) -> conv2(MFMA, in-place LDS) -> conv3(MFMA)+pool
// block = 256 thr (4 waves), t3 in [r0, r0+124), batch b. LDS: 264 lines x 128 B.
// Phase A: y1 rows l1 pair-packed 2/line, slot (pp*4+g)^(rr&7).
// Phase B chunk cc (128 rows): reads y1 lines rr=nl+kh (<=131 for cc0), then
// overwrites lines [128cc,128cc+127] -> disjoint from chunk cc+1 reads (>=128(cc+1)).
// Phase C: reads y2 lines 2*nl+kk (<=262 < 264); cols nl>=124 masked in epilogue.
__global__ __launch_bounds__(256, 4) void mega_k(const float* __restrict__ audio,
                                                 const float* __restrict__ w1,
                                                 const float* __restrict__ b1,
                                                 const u16* __restrict__ a2t,
                                                 const float* __restrict__ b2,
                                                 const u16* __restrict__ a3t,
                                                 const float* __restrict__ b3,
                                                 float* __restrict__ pooled) {
    __shared__ u16 sm[264 * 64];           // 33,792 B
    const int tid = threadIdx.x;
    const int b = blockIdx.y;
    const int r0 = blockIdx.x * NT3;
    const int lane = tid & 63, wv = tid >> 6;
    const int ls = lane >> 5, ln = lane & 31;

    // ---- Phase A: conv1 into LDS (y1 local rows 0..527; global t1 = 4*r0-12+l1)
    {
        const float* ar = audio + (size_t)b * T0;
        #pragma unroll
        for (int rep = 0; rep < 3; ++rep) {
            int l1 = rep * 256 + tid;
            if (l1 >= NROWS1) break;
            int t1 = 4 * r0 - 12 + l1;
            int rr = l1 >> 1, pp = l1 & 1;
            if (t1 < 0 || t1 >= T1) {
                u16x8 z;
                #pragma unroll
                for (int q = 0; q < 8; ++q) z[q] = 0;
                #pragma unroll
                for (int g = 0; g < 4; ++g) {
                    int slot = (pp * 4 + g) ^ (rr & 7);
                    *(u16x8*)(sm + rr * 64 + slot * 8) = z;
                }
            } else {
                int base = 2 * t1 - 4;
                float x[9];
                #pragma unroll
                for (int k = 0; k < 9; ++k) {
                    int t0v = base + k;
                    x[k] = (t0v >= 0 && t0v < T0) ? ar[t0v] : 0.f;
                }
                #pragma unroll
                for (int g = 0; g < 4; ++g) {
                    u16x8 v;
                    #pragma unroll
                    for (int j = 0; j < 8; ++j) {
                        int ch = g * 8 + j;
                        float acc = b1[ch];
                        #pragma unroll
                        for (int k = 0; k < 9; ++k) acc = fmaf(x[k], w1[ch * 9 + k], acc);
                        v[j] = f2bf(fmaxf(acc, 0.f));
                    }
                    int slot = (pp * 4 + g) ^ (rr & 7);
                    *(u16x8*)(sm + rr * 64 + slot * 8) = v;
                }
            }
        }
    }
    __syncthreads();

    // ---- Phase B: conv2 in 2 chunks of 128 y2 rows, in-place write-back
    for (int cc = 0; cc < 2; ++cc) {
        int nl = cc * 128 + 32 * wv + ln;   // this lane's y2 row (B column)
        f32x16 acc2[2];
        #pragma unroll
        for (int mi = 0; mi < 2; ++mi)
            #pragma unroll
            for (int q = 0; q < 16; ++q) acc2[mi][q] = 0.f;
        bf16x8 bfB[2];
        for (int c = 0; c < 18; ++c) {
            int kk = c >> 1;
            if ((c & 1) == 0) {
                int rr = nl + (kk >> 1);
                int pp = kk & 1;
                #pragma unroll
                for (int step = 0; step < 2; ++step) {
                    int slot = (pp * 4 + 2 * step + ls) ^ (rr & 7);
                    bfB[step] = *(const bf16x8*)(sm + rr * 64 + slot * 8);
                }
            }
            const u16* ap = a2t + c * 2048;
            #pragma unroll
            for (int step = 0; step < 2; ++step) {
                bf16x8 af0 = *(const bf16x8*)(ap + (2 * step + ls) * 512 + ln * 8);
                bf16x8 af1 = *(const bf16x8*)(ap + (2 * step + ls) * 512 + (32 + ln) * 8);
                acc2[0] = __builtin_amdgcn_mfma_f32_32x32x16_bf16(af0, bfB[step], acc2[0], 0, 0, 0);
                acc2[1] = __builtin_amdgcn_mfma_f32_32x32x16_bf16(af1, bfB[step], acc2[1], 0, 0, 0);
            }
        }
        __syncthreads();                    // all chunk reads done before overwrite
        int l2 = nl;
        int t2 = 2 * r0 - 4 + l2;
        bool valid = (t2 >= 0) && (t2 < T2);
        #pragma unroll
        for (int mi = 0; mi < 2; ++mi)
            #pragma unroll
            for (int q = 0; q < 4; ++q) {
                u16x4 v;
                #pragma unroll
                for (int d = 0; d < 4; ++d) {
                    int o = 32 * mi + 8 * q + 4 * ls + d;
                    float xv = valid ? fmaxf(acc2[mi][4 * q + d] + b2[o], 0.f) : 0.f;
                    v[d] = f2bf(xv);
                }
                int gy = 4 * mi + q;
                int sy = gy ^ ((l2 >> 1) & 7);
                *(u16x4*)(sm + l2 * 64 + sy * 8 + ls * 4) = v;
            }
        __syncthreads();
    }

    // ---- Phase C: conv3 MFMA + mean-pool (M=128 x N=128; 2x2 waves of 64x64)
    const int mh = wv & 1, nh = wv >> 1;
    f32x16 acc3[2][2];
    #pragma unroll
    for (int mi = 0; mi < 2; ++mi)
        #pragma unroll
        for (int ni = 0; ni < 2; ++ni)
            #pragma unroll
            for (int q = 0; q < 16; ++q) acc3[mi][ni][q] = 0.f;

    bf16x8 bf[2][4];
    for (int c = 0; c < 18; ++c) {
        int kk = c >> 1;
        const u16* ap = a3t + c * 8192;
        if ((c & 1) == 0) {
            #pragma unroll
            for (int ni = 0; ni < 2; ++ni) {
                int nl = 64 * nh + 32 * ni + ln;
                int l2 = 2 * nl + kk;            // <= 262 < 264
                int rrC = nl + (kk >> 1);
                #pragma unroll
                for (int step = 0; step < 4; ++step) {
                    int sy = (2 * step + ls) ^ (rrC & 7);
                    bf[ni][step] = *(const bf16x8*)(sm + l2 * 64 + sy * 8);
                }
            }
        }
        #pragma unroll
        for (int step = 0; step < 4; ++step) {
            bf16x8 af0 = *(const bf16x8*)(ap + (2 * step + ls) * 1024 + (64 * mh + ln) * 8);
            bf16x8 af1 = *(const bf16x8*)(ap + (2 * step + ls) * 1024 + (64 * mh + 32 + ln) * 8);
            #pragma unroll
            for (int ni = 0; ni < 2; ++ni) {
                acc3[0][ni] = __builtin_amdgcn_mfma_f32_32x32x16_bf16(af0, bf[ni][step], acc3[0][ni], 0, 0, 0);
                acc3[1][ni] = __builtin_amdgcn_mfma_f32_32x32x16_bf16(af1, bf[ni][step], acc3[1][ni], 0, 0, 0);
            }
        }
    }

    // epilogue: bias+relu, mask (nl>=124 local or t3>=8000 global), reduce, atomics
    float loc[32];
    #pragma unroll
    for (int mi = 0; mi < 2; ++mi)
        #pragma unroll
        for (int r = 0; r < 16; ++r) {
            int o = 64 * mh + 32 * mi + (r & 3) + 8 * (r >> 2) + 4 * ls;
            float bias = b3[o];
            float s = 0.f;
            #pragma unroll
            for (int ni = 0; ni < 2; ++ni) {
                int nl = 64 * nh + 32 * ni + ln;
                int t3 = r0 + nl;
                float v = fmaxf(acc3[mi][ni][r] + bias, 0.f);
                s += (nl < NT3 && t3 < T3) ? v : 0.f;
            }
            loc[mi * 16 + r] = s;
        }
    __syncthreads();
    float* smf = (float*)sm;               // [2 nh][128 o][32 ln] = 32 KB
    #pragma unroll
    for (int mi = 0; mi < 2; ++mi)
        #pragma unroll
        for (int r = 0; r < 16; ++r) {
            int o = 64 * mh + 32 * mi + (r & 3) + 8 * (r >> 2) + 4 * ls;
            smf[nh * 4096 + o * 32 + ln] = loc[mi * 16 + r];
        }
    __syncthreads();
    if (tid < 128) {
        int o = tid;
        float s = 0.f;
        #pragma unroll
        for (int j = 0; j < 32; ++j) {
            int col = (j + o) & 31;
            s += smf[o * 32 + col] + smf[4096 + o * 32 + col];
        }
        atomicAdd(&pooled[b * 128 + o], s);
    }
}

// ---------------- fused feats + synthesis
__global__ __launch_bounds__(256) void synth_k(const float* __restrict__ f0,
                                               const float* __restrict__ wn,
                                               const float* __restrict__ pooled,
                                               const float* __restrict__ wl,
                                               const float* __restrict__ bl,
                                               float* __restrict__ out) {
    int tid = threadIdx.x;
    int b = blockIdx.y;
    __shared__ float pl[128];
    __shared__ float red[64];
    __shared__ float sa[64];
    __shared__ float nm[64];
    if (tid < 128) pl[tid] = pooled[b * 128 + tid] * (1.0f / 8000.0f);
    __syncthreads();
    float feat = 0.f;
    if (tid < 128) {
        feat = bl[tid];
        #pragma unroll 8
        for (int i = 0; i < 128; ++i) feat = fmaf(pl[i], wl[tid * 128 + i], feat);
    }
    if (tid < 64) red[tid] = fmaxf(feat, 0.f);
    __syncthreads();
    if (tid < 32) red[tid] += red[tid + 32];
    __syncthreads();
    if (tid < 16) red[tid] += red[tid + 16];
    __syncthreads();
    if (tid < 8) red[tid] += red[tid + 8];
    __syncthreads();
    if (tid < 4) red[tid] += red[tid + 4];
    __syncthreads();
    if (tid < 2) red[tid] += red[tid + 2];
    __syncthreads();
    if (tid == 0) red[0] += red[1];
    __syncthreads();
    float denom = red[0] + 1e-6f;
    if (tid < 64) sa[tid] = fmaxf(feat, 0.f) / denom;
    else if (tid < 128) nm[tid - 64] = feat;
    __syncthreads();
    int t = blockIdx.x * 256 + tid;
    float f0v = f0[(size_t)b * T0 + t];
    // u = f0 * t * 4/63999 (linspace incl endpoint); frac in double, per-harmonic
    // frac(h*uf) exact enough in fp32 since uf in [0,1).
    double u = (double)f0v * ((double)t * (4.0 / 63999.0));
    float uf = (float)(u - floor(u));
    float acc = 0.f;
    #pragma unroll
    for (int h = 1; h <= 64; ++h) {
        float x = uf * (float)h;
        x = x - floorf(x);
        acc = fmaf(sa[h - 1], __builtin_amdgcn_sinf(x), acc);   // sin(2*pi*x)
    }
    out[(size_t)b * T0 + t] = acc + wn[(size_t)b * T0 + t] * nm[t / 1000];
}

extern "C" void kernel_launch(void* const* d_in, const int* in_sizes, int n_in,
                              void* d_out, int out_size, void* d_ws, size_t ws_size,
                              hipStream_t stream) {
    const float* audio = (const float*)d_in[0];
    const float* f0    = (const float*)d_in[1];
    const float* wn    = (const float*)d_in[2];
    const float* w1    = (const float*)d_in[3];
    const float* b1    = (const float*)d_in[4];
    const float* w2    = (const float*)d_in[5];
    const float* b2    = (const float*)d_in[6];
    const float* w3    = (const float*)d_in[7];
    const float* b3    = (const float*)d_in[8];
    const float* wl    = (const float*)d_in[9];
    const float* bl    = (const float*)d_in[10];
    float* out = (float*)d_out;

    char* ws = (char*)d_ws;
    float* pooled = (float*)(ws);                  // 2048 f32 (zeroed by prep_w_k)
    u16* a2t = (u16*)(ws + 8192);                  // 36864 u16
    u16* a3t = (u16*)(ws + 8192 + 73728);          // 147456 u16

    prep_w_k<<<728, 256, 0, stream>>>(w2, w3, a2t, a3t, pooled);
    mega_k<<<dim3(NBLK, BATCH), 256, 0, stream>>>(audio, w1, b1, a2t, b2, a3t, b3, pooled);
    synth_k<<<dim3(T0 / 256, BATCH), 256, 0, stream>>>(f0, wn, pooled, wl, bl, out);
}

// Round 7
// 201.678 us; speedup vs baseline: 1.0920x; 1.0920x over previous
//
#include <hip/hip_runtime.h>
#include <hip/hip_bf16.h>
#include <math.h>

typedef unsigned short u16;
typedef __bf16 bf16x8 __attribute__((ext_vector_type(8)));
typedef float  f32x16 __attribute__((ext_vector_type(16)));
typedef u16    u16x8  __attribute__((ext_vector_type(8)));
typedef u16    u16x4  __attribute__((ext_vector_type(4)));

#define BATCH 16
#define T0 64000
#define T1 32000
#define T2 16000
#define T3 8000
#define NT3 124          // t3 outputs per mega block; 65 blocks x 124 >= 8000
#define NBLK 65
#define NROWS1 528       // local y1 rows staged (incl. guard rows; 264 lines)
#define NL2 256          // y2 rows per block (2*124+8)

static __device__ __forceinline__ u16 f2bf(float f) {
    __hip_bfloat16 h = __float2bfloat16(f);
    return *reinterpret_cast<u16*>(&h);
}
static __device__ __forceinline__ float bf2f(u16 u) {
    __hip_bfloat16 h;
    *reinterpret_cast<u16*>(&h) = u;
    return __bfloat162float(h);
}

// ---------------- weight prep + pooled zero-init
// a2t[c][g][o][j]: c=kk*2+part (18), g=0..3 (i-granule), o=0..63, j=0..7 (i=8g+j)
// a3t[c][g][o][j]: c (18), g=0..7, o=0..127, j=0..7
__global__ __launch_bounds__(256) void prep_w_k(const float* __restrict__ w2,
                                                const float* __restrict__ w3,
                                                u16* __restrict__ a2t,
                                                u16* __restrict__ a3t,
                                                float* __restrict__ pooled) {
    int idx = blockIdx.x * 256 + threadIdx.x;
    if (idx < 36864) {
        int j = idx & 7, o = (idx >> 3) & 63, g = (idx >> 9) & 3, c = idx >> 11;
        int kk = c >> 1, part = c & 1, i = g * 8 + j;
        float v = w2[(o * 32 + i) * 9 + kk];
        u16 hv = f2bf(v);
        if (part) hv = f2bf(v - bf2f(hv));
        a2t[idx] = hv;
    } else if (idx < 36864 + 147456) {
        int jdx = idx - 36864;
        int j = jdx & 7, o = (jdx >> 3) & 127, g = (jdx >> 10) & 7, c = jdx >> 13;
        int kk = c >> 1, part = c & 1, i = g * 8 + j;
        float v = w3[(o * 64 + i) * 9 + kk];
        u16 hv = f2bf(v);
        if (part) hv = f2bf(v - bf2f(hv));
        a3t[jdx] = hv;
    } else if (idx < 36864 + 147456 + 2048) {
        pooled[idx - 36864 - 147456] = 0.f;
    }
}

// ---------------- mega: conv1(VALU) -> conv2(MFMA, in-place LDS) -> conv3(MFMA)+pool
// block = 256 thr (4 waves), t3 in [r0, r0+124), batch b. LDS: 264 lines x 128 B.
// Phase A: y1 rows l1 pair-packed 2/line, slot (pp*4+g)^(rr&7).
// Phase B chunk cc (128 rows): reads y1 lines rr=nl+kh (<=131 for cc0), then
// overwrites lines [128cc,128cc+127] -> disjoint from chunk cc+1 reads (>=128(cc+1)).
// Phase C: reads y2 lines 2*nl+kk (<=262 < 264); cols nl>=124 masked in epilogue.
// launch_bounds (256,2): cap at 256 VGPR -> ~120 actual, no spill; with <=128 VGPR
// and 33.8 KB LDS the HW still reaches 4 blocks/CU (4 waves/SIMD).
__global__ __launch_bounds__(256, 2) void mega_k(const float* __restrict__ audio,
                                                 const float* __restrict__ w1,
                                                 const float* __restrict__ b1,
                                                 const u16* __restrict__ a2t,
                                                 const float* __restrict__ b2,
                                                 const u16* __restrict__ a3t,
                                                 const float* __restrict__ b3,
                                                 float* __restrict__ pooled) {
    __shared__ u16 sm[264 * 64];           // 33,792 B
    const int tid = threadIdx.x;
    const int b = blockIdx.y;
    const int r0 = blockIdx.x * NT3;
    const int lane = tid & 63, wv = tid >> 6;
    const int ls = lane >> 5, ln = lane & 31;

    // ---- Phase A: conv1 into LDS (y1 local rows 0..527; global t1 = 4*r0-12+l1)
    {
        const float* ar = audio + (size_t)b * T0;
        #pragma unroll
        for (int rep = 0; rep < 3; ++rep) {
            int l1 = rep * 256 + tid;
            if (l1 >= NROWS1) break;
            int t1 = 4 * r0 - 12 + l1;
            int rr = l1 >> 1, pp = l1 & 1;
            if (t1 < 0 || t1 >= T1) {
                u16x8 z;
                #pragma unroll
                for (int q = 0; q < 8; ++q) z[q] = 0;
                #pragma unroll
                for (int g = 0; g < 4; ++g) {
                    int slot = (pp * 4 + g) ^ (rr & 7);
                    *(u16x8*)(sm + rr * 64 + slot * 8) = z;
                }
            } else {
                int base = 2 * t1 - 4;
                float x[9];
                #pragma unroll
                for (int k = 0; k < 9; ++k) {
                    int t0v = base + k;
                    x[k] = (t0v >= 0 && t0v < T0) ? ar[t0v] : 0.f;
                }
                #pragma unroll
                for (int g = 0; g < 4; ++g) {
                    u16x8 v;
                    #pragma unroll
                    for (int j = 0; j < 8; ++j) {
                        int ch = g * 8 + j;
                        float acc = b1[ch];
                        #pragma unroll
                        for (int k = 0; k < 9; ++k) acc = fmaf(x[k], w1[ch * 9 + k], acc);
                        v[j] = f2bf(fmaxf(acc, 0.f));
                    }
                    int slot = (pp * 4 + g) ^ (rr & 7);
                    *(u16x8*)(sm + rr * 64 + slot * 8) = v;
                }
            }
        }
    }
    __syncthreads();

    // ---- Phase B: conv2 in 2 chunks of 128 y2 rows, in-place write-back
    for (int cc = 0; cc < 2; ++cc) {
        int nl = cc * 128 + 32 * wv + ln;   // this lane's y2 row (B column)
        f32x16 acc2[2];
        #pragma unroll
        for (int mi = 0; mi < 2; ++mi)
            #pragma unroll
            for (int q = 0; q < 16; ++q) acc2[mi][q] = 0.f;
        bf16x8 bfB[2];
        for (int c = 0; c < 18; ++c) {
            int kk = c >> 1;
            if ((c & 1) == 0) {
                int rr = nl + (kk >> 1);
                int pp = kk & 1;
                #pragma unroll
                for (int step = 0; step < 2; ++step) {
                    int slot = (pp * 4 + 2 * step + ls) ^ (rr & 7);
                    bfB[step] = *(const bf16x8*)(sm + rr * 64 + slot * 8);
                }
            }
            const u16* ap = a2t + c * 2048;
            #pragma unroll
            for (int step = 0; step < 2; ++step) {
                bf16x8 af0 = *(const bf16x8*)(ap + (2 * step + ls) * 512 + ln * 8);
                bf16x8 af1 = *(const bf16x8*)(ap + (2 * step + ls) * 512 + (32 + ln) * 8);
                acc2[0] = __builtin_amdgcn_mfma_f32_32x32x16_bf16(af0, bfB[step], acc2[0], 0, 0, 0);
                acc2[1] = __builtin_amdgcn_mfma_f32_32x32x16_bf16(af1, bfB[step], acc2[1], 0, 0, 0);
            }
        }
        __syncthreads();                    // all chunk reads done before overwrite
        int l2 = nl;
        int t2 = 2 * r0 - 4 + l2;
        bool valid = (t2 >= 0) && (t2 < T2);
        #pragma unroll
        for (int mi = 0; mi < 2; ++mi)
            #pragma unroll
            for (int q = 0; q < 4; ++q) {
                u16x4 v;
                #pragma unroll
                for (int d = 0; d < 4; ++d) {
                    int o = 32 * mi + 8 * q + 4 * ls + d;
                    float xv = valid ? fmaxf(acc2[mi][4 * q + d] + b2[o], 0.f) : 0.f;
                    v[d] = f2bf(xv);
                }
                int gy = 4 * mi + q;
                int sy = gy ^ ((l2 >> 1) & 7);
                *(u16x4*)(sm + l2 * 64 + sy * 8 + ls * 4) = v;
            }
        __syncthreads();
    }

    // ---- Phase C: conv3 MFMA + mean-pool (M=128 x N=128; 2x2 waves of 64x64)
    const int mh = wv & 1, nh = wv >> 1;
    f32x16 acc3[2][2];
    #pragma unroll
    for (int mi = 0; mi < 2; ++mi)
        #pragma unroll
        for (int ni = 0; ni < 2; ++ni)
            #pragma unroll
            for (int q = 0; q < 16; ++q) acc3[mi][ni][q] = 0.f;

    bf16x8 bf[2][4];
    for (int c = 0; c < 18; ++c) {
        int kk = c >> 1;
        const u16* ap = a3t + c * 8192;
        if ((c & 1) == 0) {
            #pragma unroll
            for (int ni = 0; ni < 2; ++ni) {
                int nl = 64 * nh + 32 * ni + ln;
                int l2 = 2 * nl + kk;            // <= 262 < 264
                int rrC = nl + (kk >> 1);
                #pragma unroll
                for (int step = 0; step < 4; ++step) {
                    int sy = (2 * step + ls) ^ (rrC & 7);
                    bf[ni][step] = *(const bf16x8*)(sm + l2 * 64 + sy * 8);
                }
            }
        }
        #pragma unroll
        for (int step = 0; step < 4; ++step) {
            bf16x8 af0 = *(const bf16x8*)(ap + (2 * step + ls) * 1024 + (64 * mh + ln) * 8);
            bf16x8 af1 = *(const bf16x8*)(ap + (2 * step + ls) * 1024 + (64 * mh + 32 + ln) * 8);
            #pragma unroll
            for (int ni = 0; ni < 2; ++ni) {
                acc3[0][ni] = __builtin_amdgcn_mfma_f32_32x32x16_bf16(af0, bf[ni][step], acc3[0][ni], 0, 0, 0);
                acc3[1][ni] = __builtin_amdgcn_mfma_f32_32x32x16_bf16(af1, bf[ni][step], acc3[1][ni], 0, 0, 0);
            }
        }
    }

    // epilogue: bias+relu, mask (nl>=124 local or t3>=8000 global), reduce, atomics
    float loc[32];
    #pragma unroll
    for (int mi = 0; mi < 2; ++mi)
        #pragma unroll
        for (int r = 0; r < 16; ++r) {
            int o = 64 * mh + 32 * mi + (r & 3) + 8 * (r >> 2) + 4 * ls;
            float bias = b3[o];
            float s = 0.f;
            #pragma unroll
            for (int ni = 0; ni < 2; ++ni) {
                int nl = 64 * nh + 32 * ni + ln;
                int t3 = r0 + nl;
                float v = fmaxf(acc3[mi][ni][r] + bias, 0.f);
                s += (nl < NT3 && t3 < T3) ? v : 0.f;
            }
            loc[mi * 16 + r] = s;
        }
    __syncthreads();
    float* smf = (float*)sm;               // [2 nh][128 o][32 ln] = 32 KB
    #pragma unroll
    for (int mi = 0; mi < 2; ++mi)
        #pragma unroll
        for (int r = 0; r < 16; ++r) {
            int o = 64 * mh + 32 * mi + (r & 3) + 8 * (r >> 2) + 4 * ls;
            smf[nh * 4096 + o * 32 + ln] = loc[mi * 16 + r];
        }
    __syncthreads();
    if (tid < 128) {
        int o = tid;
        float s = 0.f;
        #pragma unroll
        for (int j = 0; j < 32; ++j) {
            int col = (j + o) & 31;
            s += smf[o * 32 + col] + smf[4096 + o * 32 + col];
        }
        atomicAdd(&pooled[b * 128 + o], s);
    }
}

// ---------------- fused feats + synthesis
__global__ __launch_bounds__(256) void synth_k(const float* __restrict__ f0,
                                               const float* __restrict__ wn,
                                               const float* __restrict__ pooled,
                                               const float* __restrict__ wl,
                                               const float* __restrict__ bl,
                                               float* __restrict__ out) {
    int tid = threadIdx.x;
    int b = blockIdx.y;
    __shared__ float pl[128];
    __shared__ float red[64];
    __shared__ float sa[64];
    __shared__ float nm[64];
    if (tid < 128) pl[tid] = pooled[b * 128 + tid] * (1.0f / 8000.0f);
    __syncthreads();
    float feat = 0.f;
    if (tid < 128) {
        feat = bl[tid];
        #pragma unroll 8
        for (int i = 0; i < 128; ++i) feat = fmaf(pl[i], wl[tid * 128 + i], feat);
    }
    if (tid < 64) red[tid] = fmaxf(feat, 0.f);
    __syncthreads();
    if (tid < 32) red[tid] += red[tid + 32];
    __syncthreads();
    if (tid < 16) red[tid] += red[tid + 16];
    __syncthreads();
    if (tid < 8) red[tid] += red[tid + 8];
    __syncthreads();
    if (tid < 4) red[tid] += red[tid + 4];
    __syncthreads();
    if (tid < 2) red[tid] += red[tid + 2];
    __syncthreads();
    if (tid == 0) red[0] += red[1];
    __syncthreads();
    float denom = red[0] + 1e-6f;
    if (tid < 64) sa[tid] = fmaxf(feat, 0.f) / denom;
    else if (tid < 128) nm[tid - 64] = feat;
    __syncthreads();
    int t = blockIdx.x * 256 + tid;
    float f0v = f0[(size_t)b * T0 + t];
    // u = f0 * t * 4/63999 (linspace incl endpoint); frac in double, per-harmonic
    // frac(h*uf) exact enough in fp32 since uf in [0,1).
    double u = (double)f0v * ((double)t * (4.0 / 63999.0));
    float uf = (float)(u - floor(u));
    float acc = 0.f;
    #pragma unroll
    for (int h = 1; h <= 64; ++h) {
        float x = uf * (float)h;
        x = x - floorf(x);
        acc = fmaf(sa[h - 1], __builtin_amdgcn_sinf(x), acc);   // sin(2*pi*x)
    }
    out[(size_t)b * T0 + t] = acc + wn[(size_t)b * T0 + t] * nm[t / 1000];
}

extern "C" void kernel_launch(void* const* d_in, const int* in_sizes, int n_in,
                              void* d_out, int out_size, void* d_ws, size_t ws_size,
                              hipStream_t stream) {
    const float* audio = (const float*)d_in[0];
    const float* f0    = (const float*)d_in[1];
    const float* wn    = (const float*)d_in[2];
    const float* w1    = (const float*)d_in[3];
    const float* b1    = (const float*)d_in[4];
    const float* w2    = (const float*)d_in[5];
    const float* b2    = (const float*)d_in[6];
    const float* w3    = (const float*)d_in[7];
    const float* b3    = (const float*)d_in[8];
    const float* wl    = (const float*)d_in[9];
    const float* bl    = (const float*)d_in[10];
    float* out = (float*)d_out;

    char* ws = (char*)d_ws;
    float* pooled = (float*)(ws);                  // 2048 f32 (zeroed by prep_w_k)
    u16* a2t = (u16*)(ws + 8192);                  // 36864 u16
    u16* a3t = (u16*)(ws + 8192 + 73728);          // 147456 u16

    prep_w_k<<<728, 256, 0, stream>>>(w2, w3, a2t, a3t, pooled);
    mega_k<<<dim3(NBLK, BATCH), 256, 0, stream>>>(audio, w1, b1, a2t, b2, a3t, b3, pooled);
    synth_k<<<dim3(T0 / 256, BATCH), 256, 0, stream>>>(f0, wn, pooled, wl, bl, out);
}

// Round 8
// 178.298 us; speedup vs baseline: 1.2351x; 1.1311x over previous
//
#include <hip/hip_runtime.h>
#include <hip/hip_bf16.h>
#include <math.h>

typedef unsigned short u16;
typedef __bf16 bf16x8 __attribute__((ext_vector_type(8)));
typedef float  f32x16 __attribute__((ext_vector_type(16)));
typedef u16    u16x8  __attribute__((ext_vector_type(8)));
typedef u16    u16x4  __attribute__((ext_vector_type(4)));

#define BATCH 16
#define T0 64000
#define T1 32000
#define T2 16000
#define T3 8000
#define NT3 250          // t3 outputs per mega block; 32 blocks x 250 = 8000 exactly
#define NBLKX 32
#define NROWS1 1040      // local y1 rows staged (520 LDS lines)

static __device__ __forceinline__ u16 f2bf(float f) {
    __hip_bfloat16 h = __float2bfloat16(f);
    return *reinterpret_cast<u16*>(&h);
}
static __device__ __forceinline__ float bf2f(u16 u) {
    __hip_bfloat16 h;
    *reinterpret_cast<u16*>(&h) = u;
    return __bfloat162float(h);
}

// ---------------- weight prep + pooled zero-init
// a2t[c][g][o][j]: c=kk*2+part (18), g=0..3 (i-granule), o=0..63, j=0..7 (i=8g+j)
// a3t[c][g][o][j]: c (18), g=0..7, o=0..127, j=0..7
__global__ __launch_bounds__(256) void prep_w_k(const float* __restrict__ w2,
                                                const float* __restrict__ w3,
                                                u16* __restrict__ a2t,
                                                u16* __restrict__ a3t,
                                                float* __restrict__ pooled) {
    int idx = blockIdx.x * 256 + threadIdx.x;
    if (idx < 36864) {
        int j = idx & 7, o = (idx >> 3) & 63, g = (idx >> 9) & 3, c = idx >> 11;
        int kk = c >> 1, part = c & 1, i = g * 8 + j;
        float v = w2[(o * 32 + i) * 9 + kk];
        u16 hv = f2bf(v);
        if (part) hv = f2bf(v - bf2f(hv));
        a2t[idx] = hv;
    } else if (idx < 36864 + 147456) {
        int jdx = idx - 36864;
        int j = jdx & 7, o = (jdx >> 3) & 127, g = (jdx >> 10) & 7, c = jdx >> 13;
        int kk = c >> 1, part = c & 1, i = g * 8 + j;
        float v = w3[(o * 64 + i) * 9 + kk];
        u16 hv = f2bf(v);
        if (part) hv = f2bf(v - bf2f(hv));
        a3t[jdx] = hv;
    } else if (idx < 36864 + 147456 + 2048) {
        pooled[idx - 36864 - 147456] = 0.f;
    }
}

// ---------------- mega: conv1(VALU) -> conv2(MFMA, in-place LDS) -> conv3(MFMA)+pool
// block = 512 thr (8 waves), t3 in [r0, r0+250), batch b. LDS: 520 lines x 128 B.
// Phase A: y1 rows l1 pair-packed 2/line, slot (pp*4+g)^(rr&7).
// Phase B chunk cc (256 rows): reads y1 lines nl+kh (<= 256cc+259), then after a
// barrier overwrites lines [256cc, 256cc+255]; chunk 1 reads lines >= 256 -> disjoint.
// Phase C: reads y2 lines 2*nl+kk (<= 518 < 520); columns nl >= 250 consume stale-y1
// lines >= 512 (finite garbage) and are masked in the epilogue.
// 512 blocks = exactly 2 blocks/CU (66.5 KB LDS), 8 waves/block -> 4 waves/SIMD.
__global__ __launch_bounds__(512, 2) void mega_k(const float* __restrict__ audio,
                                                 const float* __restrict__ w1,
                                                 const float* __restrict__ b1,
                                                 const u16* __restrict__ a2t,
                                                 const float* __restrict__ b2,
                                                 const u16* __restrict__ a3t,
                                                 const float* __restrict__ b3,
                                                 float* __restrict__ pooled) {
    __shared__ u16 sm[520 * 64];           // 66,560 B
    const int tid = threadIdx.x;
    const int b = blockIdx.y;
    const int r0 = blockIdx.x * NT3;
    const int lane = tid & 63, wv = tid >> 6;          // wv 0..7
    const int ls = lane >> 5, ln = lane & 31;

    // ---- Phase A: conv1 into LDS (y1 local rows 0..1039; global t1 = 4*r0-12+l1)
    {
        const float* ar = audio + (size_t)b * T0;
        #pragma unroll
        for (int rep = 0; rep < 3; ++rep) {
            int l1 = rep * 512 + tid;
            if (l1 >= NROWS1) break;
            int t1 = 4 * r0 - 12 + l1;
            int rr = l1 >> 1, pp = l1 & 1;
            if (t1 < 0 || t1 >= T1) {
                u16x8 z;
                #pragma unroll
                for (int q = 0; q < 8; ++q) z[q] = 0;
                #pragma unroll
                for (int g = 0; g < 4; ++g) {
                    int slot = (pp * 4 + g) ^ (rr & 7);
                    *(u16x8*)(sm + rr * 64 + slot * 8) = z;
                }
            } else {
                int base = 2 * t1 - 4;
                float x[9];
                #pragma unroll
                for (int k = 0; k < 9; ++k) {
                    int t0v = base + k;
                    x[k] = (t0v >= 0 && t0v < T0) ? ar[t0v] : 0.f;
                }
                #pragma unroll
                for (int g = 0; g < 4; ++g) {
                    u16x8 v;
                    #pragma unroll
                    for (int j = 0; j < 8; ++j) {
                        int ch = g * 8 + j;
                        float acc = b1[ch];
                        #pragma unroll
                        for (int k = 0; k < 9; ++k) acc = fmaf(x[k], w1[ch * 9 + k], acc);
                        v[j] = f2bf(fmaxf(acc, 0.f));
                    }
                    int slot = (pp * 4 + g) ^ (rr & 7);
                    *(u16x8*)(sm + rr * 64 + slot * 8) = v;
                }
            }
        }
    }
    __syncthreads();

    // ---- Phase B: conv2 in 2 chunks of 256 y2 rows, in-place write-back
    for (int cc = 0; cc < 2; ++cc) {
        int nl = cc * 256 + 32 * wv + ln;   // this lane's y2 row (B column)
        f32x16 acc2[2];
        #pragma unroll
        for (int mi = 0; mi < 2; ++mi)
            #pragma unroll
            for (int q = 0; q < 16; ++q) acc2[mi][q] = 0.f;
        bf16x8 bfB[2];
        #pragma unroll 2
        for (int c = 0; c < 18; ++c) {
            int kk = c >> 1;
            if ((c & 1) == 0) {
                int rr = nl + (kk >> 1);
                int pp = kk & 1;
                #pragma unroll
                for (int step = 0; step < 2; ++step) {
                    int slot = (pp * 4 + 2 * step + ls) ^ (rr & 7);
                    bfB[step] = *(const bf16x8*)(sm + rr * 64 + slot * 8);
                }
            }
            const u16* ap = a2t + c * 2048;
            #pragma unroll
            for (int step = 0; step < 2; ++step) {
                bf16x8 af0 = *(const bf16x8*)(ap + (2 * step + ls) * 512 + ln * 8);
                bf16x8 af1 = *(const bf16x8*)(ap + (2 * step + ls) * 512 + (32 + ln) * 8);
                acc2[0] = __builtin_amdgcn_mfma_f32_32x32x16_bf16(af0, bfB[step], acc2[0], 0, 0, 0);
                acc2[1] = __builtin_amdgcn_mfma_f32_32x32x16_bf16(af1, bfB[step], acc2[1], 0, 0, 0);
            }
        }
        __syncthreads();                    // all chunk reads done before overwrite
        int l2 = nl;
        int t2 = 2 * r0 - 4 + l2;
        bool valid = (t2 >= 0) && (t2 < T2);
        #pragma unroll
        for (int mi = 0; mi < 2; ++mi)
            #pragma unroll
            for (int q = 0; q < 4; ++q) {
                u16x4 v;
                #pragma unroll
                for (int d = 0; d < 4; ++d) {
                    int o = 32 * mi + 8 * q + 4 * ls + d;
                    float xv = valid ? fmaxf(acc2[mi][4 * q + d] + b2[o], 0.f) : 0.f;
                    v[d] = f2bf(xv);
                }
                int gy = 4 * mi + q;
                int sy = gy ^ ((l2 >> 1) & 7);
                *(u16x4*)(sm + l2 * 64 + sy * 8 + ls * 4) = v;
            }
        __syncthreads();
    }

    // ---- Phase C: conv3 MFMA + mean-pool (M=128 x N=256; 2x4 waves of 64x64)
    const int mh = wv & 1, nh = wv >> 1;               // mh 0..1, nh 0..3
    f32x16 acc3[2][2];
    #pragma unroll
    for (int mi = 0; mi < 2; ++mi)
        #pragma unroll
        for (int ni = 0; ni < 2; ++ni)
            #pragma unroll
            for (int q = 0; q < 16; ++q) acc3[mi][ni][q] = 0.f;

    bf16x8 bf[2][4];
    #pragma unroll 2
    for (int c = 0; c < 18; ++c) {
        int kk = c >> 1;
        const u16* ap = a3t + c * 8192;
        if ((c & 1) == 0) {
            #pragma unroll
            for (int ni = 0; ni < 2; ++ni) {
                int nl = 64 * nh + 32 * ni + ln;
                int l2 = 2 * nl + kk;                  // <= 518 < 520
                int rrC = nl + (kk >> 1);
                #pragma unroll
                for (int step = 0; step < 4; ++step) {
                    int sy = (2 * step + ls) ^ (rrC & 7);
                    bf[ni][step] = *(const bf16x8*)(sm + l2 * 64 + sy * 8);
                }
            }
        }
        #pragma unroll
        for (int step = 0; step < 4; ++step) {
            bf16x8 af0 = *(const bf16x8*)(ap + (2 * step + ls) * 1024 + (64 * mh + ln) * 8);
            bf16x8 af1 = *(const bf16x8*)(ap + (2 * step + ls) * 1024 + (64 * mh + 32 + ln) * 8);
            #pragma unroll
            for (int ni = 0; ni < 2; ++ni) {
                acc3[0][ni] = __builtin_amdgcn_mfma_f32_32x32x16_bf16(af0, bf[ni][step], acc3[0][ni], 0, 0, 0);
                acc3[1][ni] = __builtin_amdgcn_mfma_f32_32x32x16_bf16(af1, bf[ni][step], acc3[1][ni], 0, 0, 0);
            }
        }
    }

    // epilogue: bias+relu, mask nl>=250, per-wave partials -> LDS reduce -> atomics
    float loc[32];
    #pragma unroll
    for (int mi = 0; mi < 2; ++mi)
        #pragma unroll
        for (int r = 0; r < 16; ++r) {
            int o = 64 * mh + 32 * mi + (r & 3) + 8 * (r >> 2) + 4 * ls;
            float bias = b3[o];
            float s = 0.f;
            #pragma unroll
            for (int ni = 0; ni < 2; ++ni) {
                int nl = 64 * nh + 32 * ni + ln;
                float v = fmaxf(acc3[mi][ni][r] + bias, 0.f);
                s += (nl < NT3) ? v : 0.f;
            }
            loc[mi * 16 + r] = s;
        }
    __syncthreads();
    float* smf = (float*)sm;               // [4 nh][128 o][32 ln] = 64 KB <= 66,560 B
    #pragma unroll
    for (int mi = 0; mi < 2; ++mi)
        #pragma unroll
        for (int r = 0; r < 16; ++r) {
            int o = 64 * mh + 32 * mi + (r & 3) + 8 * (r >> 2) + 4 * ls;
            smf[nh * 4096 + o * 32 + ln] = loc[mi * 16 + r];
        }
    __syncthreads();
    if (tid < 128) {
        int o = tid;
        float s = 0.f;
        #pragma unroll
        for (int j = 0; j < 32; ++j) {
            int col = (j + o) & 31;
            s += smf[o * 32 + col] + smf[4096 + o * 32 + col]
               + smf[8192 + o * 32 + col] + smf[12288 + o * 32 + col];
        }
        atomicAdd(&pooled[b * 128 + o], s);
    }
}

// ---------------- fused feats + synthesis
__global__ __launch_bounds__(256) void synth_k(const float* __restrict__ f0,
                                               const float* __restrict__ wn,
                                               const float* __restrict__ pooled,
                                               const float* __restrict__ wl,
                                               const float* __restrict__ bl,
                                               float* __restrict__ out) {
    int tid = threadIdx.x;
    int b = blockIdx.y;
    __shared__ float pl[128];
    __shared__ float red[64];
    __shared__ float sa[64];
    __shared__ float nm[64];
    if (tid < 128) pl[tid] = pooled[b * 128 + tid] * (1.0f / 8000.0f);
    __syncthreads();
    float feat = 0.f;
    if (tid < 128) {
        feat = bl[tid];
        #pragma unroll 8
        for (int i = 0; i < 128; ++i) feat = fmaf(pl[i], wl[tid * 128 + i], feat);
    }
    if (tid < 64) red[tid] = fmaxf(feat, 0.f);
    __syncthreads();
    if (tid < 32) red[tid] += red[tid + 32];
    __syncthreads();
    if (tid < 16) red[tid] += red[tid + 16];
    __syncthreads();
    if (tid < 8) red[tid] += red[tid + 8];
    __syncthreads();
    if (tid < 4) red[tid] += red[tid + 4];
    __syncthreads();
    if (tid < 2) red[tid] += red[tid + 2];
    __syncthreads();
    if (tid == 0) red[0] += red[1];
    __syncthreads();
    float denom = red[0] + 1e-6f;
    if (tid < 64) sa[tid] = fmaxf(feat, 0.f) / denom;
    else if (tid < 128) nm[tid - 64] = feat;
    __syncthreads();
    int t = blockIdx.x * 256 + tid;
    float f0v = f0[(size_t)b * T0 + t];
    // u = f0 * t * 4/63999 (linspace incl endpoint); frac in double, per-harmonic
    // frac(h*uf) exact enough in fp32 since uf in [0,1).
    double u = (double)f0v * ((double)t * (4.0 / 63999.0));
    float uf = (float)(u - floor(u));
    float acc = 0.f;
    #pragma unroll
    for (int h = 1; h <= 64; ++h) {
        float x = uf * (float)h;
        x = x - floorf(x);
        acc = fmaf(sa[h - 1], __builtin_amdgcn_sinf(x), acc);   // sin(2*pi*x)
    }
    out[(size_t)b * T0 + t] = acc + wn[(size_t)b * T0 + t] * nm[t / 1000];
}

extern "C" void kernel_launch(void* const* d_in, const int* in_sizes, int n_in,
                              void* d_out, int out_size, void* d_ws, size_t ws_size,
                              hipStream_t stream) {
    const float* audio = (const float*)d_in[0];
    const float* f0    = (const float*)d_in[1];
    const float* wn    = (const float*)d_in[2];
    const float* w1    = (const float*)d_in[3];
    const float* b1    = (const float*)d_in[4];
    const float* w2    = (const float*)d_in[5];
    const float* b2    = (const float*)d_in[6];
    const float* w3    = (const float*)d_in[7];
    const float* b3    = (const float*)d_in[8];
    const float* wl    = (const float*)d_in[9];
    const float* bl    = (const float*)d_in[10];
    float* out = (float*)d_out;

    char* ws = (char*)d_ws;
    float* pooled = (float*)(ws);                  // 2048 f32 (zeroed by prep_w_k)
    u16* a2t = (u16*)(ws + 8192);                  // 36864 u16
    u16* a3t = (u16*)(ws + 8192 + 73728);          // 147456 u16

    prep_w_k<<<728, 256, 0, stream>>>(w2, w3, a2t, a3t, pooled);
    mega_k<<<dim3(NBLKX, BATCH), 512, 0, stream>>>(audio, w1, b1, a2t, b2, a3t, b3, pooled);
    synth_k<<<dim3(T0 / 256, BATCH), 256, 0, stream>>>(f0, wn, pooled, wl, bl, out);
}

// Round 9
// 155.209 us; speedup vs baseline: 1.4189x; 1.1488x over previous
//
#include <hip/hip_runtime.h>
#include <hip/hip_bf16.h>
#include <math.h>

typedef unsigned short u16;
typedef _Float16 f16x8 __attribute__((ext_vector_type(8)));
typedef float    f32x16 __attribute__((ext_vector_type(16)));
typedef u16      u16x8  __attribute__((ext_vector_type(8)));
typedef u16      u16x4  __attribute__((ext_vector_type(4)));

#define BATCH 16
#define T0 64000
#define T1 32000
#define T2 16000
#define T3 8000
#define NT3 250          // t3 outputs per mega block; 32 blocks x 250 = 8000 exactly
#define NBLKX 32
#define NROWS1 1040      // local y1 rows staged (520 LDS lines)

static __device__ __forceinline__ u16 f2h(float f) {
    _Float16 h = (_Float16)f;
    u16 u;
    __builtin_memcpy(&u, &h, 2);
    return u;
}

// ---------------- weight prep (f16, transposed for coalesced A-frag reads) + pooled zero
// a2t[kk][g][o][j]: kk 0..8, g=0..3 (i-granule), o=0..63, j=0..7 (i=8g+j)   18432 u16
// a3t[kk][g][o][j]: kk 0..8, g=0..7,              o=0..127, j=0..7          73728 u16
__global__ __launch_bounds__(256) void prep_w_k(const float* __restrict__ w2,
                                                const float* __restrict__ w3,
                                                u16* __restrict__ a2t,
                                                u16* __restrict__ a3t,
                                                float* __restrict__ pooled) {
    int idx = blockIdx.x * 256 + threadIdx.x;
    if (idx < 18432) {
        int j = idx & 7, o = (idx >> 3) & 63, g = (idx >> 9) & 3, kk = idx >> 11;
        a2t[idx] = f2h(w2[(o * 32 + g * 8 + j) * 9 + kk]);
    } else if (idx < 18432 + 73728) {
        int jdx = idx - 18432;
        int j = jdx & 7, o = (jdx >> 3) & 127, g = (jdx >> 10) & 7, kk = jdx >> 13;
        a3t[jdx] = f2h(w3[(o * 64 + g * 8 + j) * 9 + kk]);
    } else if (idx < 18432 + 73728 + 2048) {
        pooled[idx - 18432 - 73728] = 0.f;
    }
}

// ---------------- mega: conv1(VALU) -> conv2(MFMA, in-place LDS) -> conv3(MFMA)+pool
// block = 512 thr (8 waves), t3 in [r0, r0+250), batch b. LDS: 520 lines x 128 B.
// All activations/weights f16 (0.05% rounding; no hi/lo split needed -> 9 K-iters).
// Phase A: y1 rows l1 pair-packed 2/line, slot (pp*4+g)^(rr&7).
// Phase B chunk cc (256 rows): reads y1 lines nl+kh (<= 256cc+259), then after a
// barrier overwrites lines [256cc, 256cc+255]; chunk 1 reads lines >= 256 -> disjoint.
// Phase C: reads y2 lines 2*nl+kk (<= 518 < 520); columns nl >= 250 consume stale
// (finite) data and are masked in the epilogue.
// 512 blocks = exactly 2 blocks/CU (66.5 KB LDS), 8 waves/block -> 4 waves/SIMD.
__global__ __launch_bounds__(512, 2) void mega_k(const float* __restrict__ audio,
                                                 const float* __restrict__ w1,
                                                 const float* __restrict__ b1,
                                                 const u16* __restrict__ a2t,
                                                 const float* __restrict__ b2,
                                                 const u16* __restrict__ a3t,
                                                 const float* __restrict__ b3,
                                                 float* __restrict__ pooled) {
    __shared__ u16 sm[520 * 64];           // 66,560 B
    const int tid = threadIdx.x;
    const int b = blockIdx.y;
    const int r0 = blockIdx.x * NT3;
    const int lane = tid & 63, wv = tid >> 6;          // wv 0..7
    const int ls = lane >> 5, ln = lane & 31;

    // ---- Phase A: conv1 into LDS (y1 local rows 0..1039; global t1 = 4*r0-12+l1)
    {
        const float* ar = audio + (size_t)b * T0;
        #pragma unroll
        for (int rep = 0; rep < 3; ++rep) {
            int l1 = rep * 512 + tid;
            if (l1 >= NROWS1) break;
            int t1 = 4 * r0 - 12 + l1;
            int rr = l1 >> 1, pp = l1 & 1;
            if (t1 < 0 || t1 >= T1) {
                u16x8 z;
                #pragma unroll
                for (int q = 0; q < 8; ++q) z[q] = 0;
                #pragma unroll
                for (int g = 0; g < 4; ++g) {
                    int slot = (pp * 4 + g) ^ (rr & 7);
                    *(u16x8*)(sm + rr * 64 + slot * 8) = z;
                }
            } else {
                int base = 2 * t1 - 4;
                float x[9];
                #pragma unroll
                for (int k = 0; k < 9; ++k) {
                    int t0v = base + k;
                    x[k] = (t0v >= 0 && t0v < T0) ? ar[t0v] : 0.f;
                }
                #pragma unroll
                for (int g = 0; g < 4; ++g) {
                    u16x8 v;
                    #pragma unroll
                    for (int j = 0; j < 8; ++j) {
                        int ch = g * 8 + j;
                        float acc = b1[ch];
                        #pragma unroll
                        for (int k = 0; k < 9; ++k) acc = fmaf(x[k], w1[ch * 9 + k], acc);
                        v[j] = f2h(fmaxf(acc, 0.f));
                    }
                    int slot = (pp * 4 + g) ^ (rr & 7);
                    *(u16x8*)(sm + rr * 64 + slot * 8) = v;
                }
            }
        }
    }
    __syncthreads();

    // ---- Phase B: conv2 in 2 chunks of 256 y2 rows, in-place write-back
    for (int cc = 0; cc < 2; ++cc) {
        int nl = cc * 256 + 32 * wv + ln;   // this lane's y2 row (B column)
        f32x16 acc2[2];
        #pragma unroll
        for (int mi = 0; mi < 2; ++mi)
            #pragma unroll
            for (int q = 0; q < 16; ++q) acc2[mi][q] = 0.f;
        f16x8 bfB[2];
        #pragma unroll 3
        for (int kk = 0; kk < 9; ++kk) {
            {
                int rr = nl + (kk >> 1);
                int pp = kk & 1;
                #pragma unroll
                for (int step = 0; step < 2; ++step) {
                    int slot = (pp * 4 + 2 * step + ls) ^ (rr & 7);
                    bfB[step] = *(const f16x8*)(sm + rr * 64 + slot * 8);
                }
            }
            const u16* ap = a2t + kk * 2048;
            #pragma unroll
            for (int step = 0; step < 2; ++step) {
                f16x8 af0 = *(const f16x8*)(ap + (2 * step + ls) * 512 + ln * 8);
                f16x8 af1 = *(const f16x8*)(ap + (2 * step + ls) * 512 + (32 + ln) * 8);
                acc2[0] = __builtin_amdgcn_mfma_f32_32x32x16_f16(af0, bfB[step], acc2[0], 0, 0, 0);
                acc2[1] = __builtin_amdgcn_mfma_f32_32x32x16_f16(af1, bfB[step], acc2[1], 0, 0, 0);
            }
        }
        __syncthreads();                    // all chunk reads done before overwrite
        int l2 = nl;
        int t2 = 2 * r0 - 4 + l2;
        bool valid = (t2 >= 0) && (t2 < T2);
        #pragma unroll
        for (int mi = 0; mi < 2; ++mi)
            #pragma unroll
            for (int q = 0; q < 4; ++q) {
                u16x4 v;
                #pragma unroll
                for (int d = 0; d < 4; ++d) {
                    int o = 32 * mi + 8 * q + 4 * ls + d;
                    float xv = valid ? fmaxf(acc2[mi][4 * q + d] + b2[o], 0.f) : 0.f;
                    v[d] = f2h(xv);
                }
                int gy = 4 * mi + q;
                int sy = gy ^ ((l2 >> 1) & 7);
                *(u16x4*)(sm + l2 * 64 + sy * 8 + ls * 4) = v;
            }
        __syncthreads();
    }

    // ---- Phase C: conv3 MFMA + mean-pool (M=128 x N=256; 2x4 waves of 64x64)
    const int mh = wv & 1, nh = wv >> 1;               // mh 0..1, nh 0..3
    f32x16 acc3[2][2];
    #pragma unroll
    for (int mi = 0; mi < 2; ++mi)
        #pragma unroll
        for (int ni = 0; ni < 2; ++ni)
            #pragma unroll
            for (int q = 0; q < 16; ++q) acc3[mi][ni][q] = 0.f;

    f16x8 bf[2][4];
    #pragma unroll 3
    for (int kk = 0; kk < 9; ++kk) {
        const u16* ap = a3t + kk * 8192;
        {
            #pragma unroll
            for (int ni = 0; ni < 2; ++ni) {
                int nl = 64 * nh + 32 * ni + ln;
                int l2 = 2 * nl + kk;                  // <= 518 < 520
                int rrC = nl + (kk >> 1);
                #pragma unroll
                for (int step = 0; step < 4; ++step) {
                    int sy = (2 * step + ls) ^ (rrC & 7);
                    bf[ni][step] = *(const f16x8*)(sm + l2 * 64 + sy * 8);
                }
            }
        }
        #pragma unroll
        for (int step = 0; step < 4; ++step) {
            f16x8 af0 = *(const f16x8*)(ap + (2 * step + ls) * 1024 + (64 * mh + ln) * 8);
            f16x8 af1 = *(const f16x8*)(ap + (2 * step + ls) * 1024 + (64 * mh + 32 + ln) * 8);
            #pragma unroll
            for (int ni = 0; ni < 2; ++ni) {
                acc3[0][ni] = __builtin_amdgcn_mfma_f32_32x32x16_f16(af0, bf[ni][step], acc3[0][ni], 0, 0, 0);
                acc3[1][ni] = __builtin_amdgcn_mfma_f32_32x32x16_f16(af1, bf[ni][step], acc3[1][ni], 0, 0, 0);
            }
        }
    }

    // epilogue: bias+relu, mask nl>=250, per-wave partials -> LDS reduce -> atomics
    float loc[32];
    #pragma unroll
    for (int mi = 0; mi < 2; ++mi)
        #pragma unroll
        for (int r = 0; r < 16; ++r) {
            int o = 64 * mh + 32 * mi + (r & 3) + 8 * (r >> 2) + 4 * ls;
            float bias = b3[o];
            float s = 0.f;
            #pragma unroll
            for (int ni = 0; ni < 2; ++ni) {
                int nl = 64 * nh + 32 * ni + ln;
                float v = fmaxf(acc3[mi][ni][r] + bias, 0.f);
                s += (nl < NT3) ? v : 0.f;
            }
            loc[mi * 16 + r] = s;
        }
    __syncthreads();
    float* smf = (float*)sm;               // [4 nh][128 o][32 ln] = 64 KB <= 66,560 B
    #pragma unroll
    for (int mi = 0; mi < 2; ++mi)
        #pragma unroll
        for (int r = 0; r < 16; ++r) {
            int o = 64 * mh + 32 * mi + (r & 3) + 8 * (r >> 2) + 4 * ls;
            smf[nh * 4096 + o * 32 + ln] = loc[mi * 16 + r];
        }
    __syncthreads();
    if (tid < 128) {
        int o = tid;
        float s = 0.f;
        #pragma unroll
        for (int j = 0; j < 32; ++j) {
            int col = (j + o) & 31;
            s += smf[o * 32 + col] + smf[4096 + o * 32 + col]
               + smf[8192 + o * 32 + col] + smf[12288 + o * 32 + col];
        }
        atomicAdd(&pooled[b * 128 + o], s);
    }
}

// ---------------- fused feats + synthesis
__global__ __launch_bounds__(256) void synth_k(const float* __restrict__ f0,
                                               const float* __restrict__ wn,
                                               const float* __restrict__ pooled,
                                               const float* __restrict__ wl,
                                               const float* __restrict__ bl,
                                               float* __restrict__ out) {
    int tid = threadIdx.x;
    int b = blockIdx.y;
    __shared__ float pl[128];
    __shared__ float red[64];
    __shared__ float sa[64];
    __shared__ float nm[64];
    if (tid < 128) pl[tid] = pooled[b * 128 + tid] * (1.0f / 8000.0f);
    __syncthreads();
    float feat = 0.f;
    if (tid < 128) {
        feat = bl[tid];
        #pragma unroll 8
        for (int i = 0; i < 128; ++i) feat = fmaf(pl[i], wl[tid * 128 + i], feat);
    }
    if (tid < 64) red[tid] = fmaxf(feat, 0.f);
    __syncthreads();
    if (tid < 32) red[tid] += red[tid + 32];
    __syncthreads();
    if (tid < 16) red[tid] += red[tid + 16];
    __syncthreads();
    if (tid < 8) red[tid] += red[tid + 8];
    __syncthreads();
    if (tid < 4) red[tid] += red[tid + 4];
    __syncthreads();
    if (tid < 2) red[tid] += red[tid + 2];
    __syncthreads();
    if (tid == 0) red[0] += red[1];
    __syncthreads();
    float denom = red[0] + 1e-6f;
    if (tid < 64) sa[tid] = fmaxf(feat, 0.f) / denom;
    else if (tid < 128) nm[tid - 64] = feat;
    __syncthreads();
    int t = blockIdx.x * 256 + tid;
    float f0v = f0[(size_t)b * T0 + t];
    // u = f0 * t * 4/63999 (linspace incl endpoint); frac in double, per-harmonic
    // frac(h*uf) exact enough in fp32 since uf in [0,1).
    double u = (double)f0v * ((double)t * (4.0 / 63999.0));
    float uf = (float)(u - floor(u));
    float acc = 0.f;
    #pragma unroll
    for (int h = 1; h <= 64; ++h) {
        float x = uf * (float)h;
        x = x - floorf(x);
        acc = fmaf(sa[h - 1], __builtin_amdgcn_sinf(x), acc);   // sin(2*pi*x)
    }
    out[(size_t)b * T0 + t] = acc + wn[(size_t)b * T0 + t] * nm[t / 1000];
}

extern "C" void kernel_launch(void* const* d_in, const int* in_sizes, int n_in,
                              void* d_out, int out_size, void* d_ws, size_t ws_size,
                              hipStream_t stream) {
    const float* audio = (const float*)d_in[0];
    const float* f0    = (const float*)d_in[1];
    const float* wn    = (const float*)d_in[2];
    const float* w1    = (const float*)d_in[3];
    const float* b1    = (const float*)d_in[4];
    const float* w2    = (const float*)d_in[5];
    const float* b2    = (const float*)d_in[6];
    const float* w3    = (const float*)d_in[7];
    const float* b3    = (const float*)d_in[8];
    const float* wl    = (const float*)d_in[9];
    const float* bl    = (const float*)d_in[10];
    float* out = (float*)d_out;

    char* ws = (char*)d_ws;
    float* pooled = (float*)(ws);                  // 2048 f32 (zeroed by prep_w_k)
    u16* a2t = (u16*)(ws + 8192);                  // 18432 u16
    u16* a3t = (u16*)(ws + 8192 + 36864);          // 73728 u16

    prep_w_k<<<368, 256, 0, stream>>>(w2, w3, a2t, a3t, pooled);
    mega_k<<<dim3(NBLKX, BATCH), 512, 0, stream>>>(audio, w1, b1, a2t, b2, a3t, b3, pooled);
    synth_k<<<dim3(T0 / 256, BATCH), 256, 0, stream>>>(f0, wn, pooled, wl, bl, out);
}